// Round 4
// baseline (41.515 us; speedup 1.0000x reference)
//
#include <hip/hip_runtime.h>
#include <hip/hip_bf16.h>
#include <math.h>

#define QN 8192
#define CN 64
#define SHOT 5
#define DN 512

#define THREADS 256
#define NWAVES 4
#define TQ 4
#define QPB (NWAVES * TQ)          // 16 queries/block -> grid 512 = 2 blocks/CU
#define DCHUNK 128
#define F4C (DCHUNK / 4)           // 32 float4 per class-row chunk
#define NCHUNK (DN / DCHUNK)       // 4
#define DMA_PER_WAVE 10            // 8 proto + 2 x instrs per wave per chunk

// --- proto kernel: mean over SHOT, written PRE-SWIZZLED for linear DMA ---
// LDS image wanted: chunk[c][fs] = P[c][chunk][fs ^ (c&7)]  (f4 units)
// so store P[c][g] (g = global f4 idx) at ws f4 idx  c*128 + (g&~31) | ((g&31)^(c&7))
__global__ void proto_kernel(const float* __restrict__ y, float* __restrict__ pws) {
    int idx = blockIdx.x * blockDim.x + threadIdx.x;   // 0 .. C*D-1
    if (idx < CN * DN) {
        int c = idx >> 9;          // / 512
        int d = idx & (DN - 1);
        float s = 0.f;
#pragma unroll
        for (int sh = 0; sh < SHOT; ++sh)
            s += y[(c * SHOT + sh) * DN + d];
        int g   = d >> 2;
        int sub = d & 3;
        int gs  = (g & ~31) | ((g & 31) ^ (c & 7));
        pws[c * DN + gs * 4 + sub] = s * (1.0f / SHOT);
    }
}

// --- main kernel: lane = class; proto + x both DMA'd to LDS, double-buffered ---
__global__ __launch_bounds__(THREADS, 2) void dist_softmax_kernel(
        const float* __restrict__ x,
        const float* __restrict__ pws,
        float* __restrict__ out) {
    __shared__ float4 pbuf[2][CN * F4C];    // 2 x 32 KiB, [c][fs] swizzled rows
    __shared__ float4 xbuf[2][QPB * F4C];   // 2 x 8 KiB,  [q_local][f] linear rows

    const int tid  = threadIdx.x;
    const int lane = tid & 63;
    const int wave = __builtin_amdgcn_readfirstlane(tid >> 6);
    const int q0b  = blockIdx.x * QPB;
    const int lhi  = lane >> 5;             // 0/1: which row of the 1KB DMA pair
    const int llo  = lane & 31;             // f4 within row-chunk

    // issue one chunk's DMA: exactly DMA_PER_WAVE instrs per wave (countable vmcnt)
    auto issue = [&](int k) {
        const int buf = k & 1;
#pragma unroll
        for (int t = 0; t < 8; ++t) {
            int i = wave * 8 + t;           // covers classes 2i, 2i+1
            const float* src = pws + (((2 * i + lhi) * (DN / 4) + k * F4C + llo) << 2);
            __builtin_amdgcn_global_load_lds(
                (const __attribute__((address_space(1))) void*)src,
                (__attribute__((address_space(3))) void*)&pbuf[buf][i * 64], 16, 0, 0);
        }
#pragma unroll
        for (int t = 0; t < 2; ++t) {
            int j = wave * 2 + t;           // covers q rows 2j, 2j+1
            const float* src = x + (((q0b + 2 * j + lhi) * (DN / 4) + k * F4C + llo) << 2);
            __builtin_amdgcn_global_load_lds(
                (const __attribute__((address_space(1))) void*)src,
                (__attribute__((address_space(3))) void*)&xbuf[buf][j * 64], 16, 0, 0);
        }
    };

    float acc0 = 0.f, acc1 = 0.f, acc2 = 0.f, acc3 = 0.f;

    issue(0);
    for (int k = 0; k < NCHUNK; ++k) {
        if (k < NCHUNK - 1) {
            issue(k + 1);                    // keep next chunk in flight across barrier
            asm volatile("s_waitcnt vmcnt(10)" ::: "memory");   // chunk k landed
        } else {
            asm volatile("s_waitcnt vmcnt(0)" ::: "memory");
        }
        __builtin_amdgcn_s_barrier();        // publish chunk k
        __builtin_amdgcn_sched_barrier(0);

        const float4* pB = pbuf[k & 1] + lane * F4C;        // my class row (swizzled)
        const float4* xB = xbuf[k & 1] + (wave * TQ) * F4C; // my 4 query rows (uniform)
        const int ls7 = lane & 7;
#pragma unroll 8
        for (int f = 0; f < F4C; ++f) {
            float4 p  = pB[f ^ ls7];
            float4 a0 = xB[f];
            float4 a1 = xB[F4C + f];
            float4 a2 = xB[2 * F4C + f];
            float4 a3 = xB[3 * F4C + f];
            acc0 += fabsf(a0.x - p.x) + fabsf(a0.y - p.y) + fabsf(a0.z - p.z) + fabsf(a0.w - p.w);
            acc1 += fabsf(a1.x - p.x) + fabsf(a1.y - p.y) + fabsf(a1.z - p.z) + fabsf(a1.w - p.w);
            acc2 += fabsf(a2.x - p.x) + fabsf(a2.y - p.y) + fabsf(a2.z - p.z) + fabsf(a2.w - p.w);
            acc3 += fabsf(a3.x - p.x) + fabsf(a3.y - p.y) + fabsf(a3.z - p.z) + fabsf(a3.w - p.w);
        }
        __builtin_amdgcn_s_barrier();        // all waves done reading before overwrite
    }

    // softmax over classes (= lanes) for the wave's 4 queries
    float accs[TQ] = {acc0, acc1, acc2, acc3};
#pragma unroll
    for (int qi = 0; qi < TQ; ++qi) {
        float nd = -accs[qi];
        float m = nd;
#pragma unroll
        for (int off = 32; off; off >>= 1)
            m = fmaxf(m, __shfl_xor(m, off, 64));
        float e = __expf(nd - m);
        float s = e;
#pragma unroll
        for (int off = 32; off; off >>= 1)
            s += __shfl_xor(s, off, 64);
        out[(q0b + wave * TQ + qi) * CN + lane] = e / s;
    }
}

extern "C" void kernel_launch(void* const* d_in, const int* in_sizes, int n_in,
                              void* d_out, int out_size, void* d_ws, size_t ws_size,
                              hipStream_t stream) {
    const float* x = (const float*)d_in[0];   // [8192, 512]
    const float* y = (const float*)d_in[1];   // [64, 5, 512]
    float* out     = (float*)d_out;           // [8192, 64]
    float* pws     = (float*)d_ws;            // [64, 512] swizzled proto scratch

    proto_kernel<<<(CN * DN + 255) / 256, 256, 0, stream>>>(y, pws);
    dist_softmax_kernel<<<QN / QPB, THREADS, 0, stream>>>(x, pws, out);
}

// Round 5
// 31.241 us; speedup vs baseline: 1.3289x; 1.3289x over previous
//
#include <hip/hip_runtime.h>
#include <hip/hip_bf16.h>
#include <math.h>

#define QN 8192
#define CN 64
#define SHOT 5
#define DN 512

#define SPLIT 4
#define DSLICE (DN / SPLIT)     // 128 d's per block
#define F4S (DSLICE / 4)        // 32 float4 per class-slice row
#define THREADS 256
#define NWAVES 4
#define TQ 8
#define QPB (NWAVES * TQ)       // 32 queries per block

// --- proto kernel: proto[c][d] = mean over SHOT of y[c][s][d] ---
__global__ void proto_kernel(const float* __restrict__ y, float* __restrict__ proto) {
    int idx = blockIdx.x * blockDim.x + threadIdx.x;   // 0 .. C*D-1
    if (idx < CN * DN) {
        int c = idx >> 9;
        int d = idx & (DN - 1);
        float s = 0.f;
#pragma unroll
        for (int sh = 0; sh < SHOT; ++sh)
            s += y[(c * SHOT + sh) * DN + d];
        proto[idx] = s * (1.0f / SHOT);
    }
}

// --- dist kernel: lane = class, wave = 8 queries, block = one 128-d slice ---
// partial[split][q][c] = sum over that slice of |x - proto|
__global__ __launch_bounds__(THREADS, 4) void dist_kernel(
        const float* __restrict__ x,
        const float* __restrict__ proto,
        float* __restrict__ partial) {
    __shared__ float4 plds[CN * F4S];   // 64 x 32 float4 = 32 KiB, XOR-swizzled

    const int tid   = threadIdx.x;
    const int lane  = tid & 63;
    const int wave  = __builtin_amdgcn_readfirstlane(tid >> 6);
    const int split = blockIdx.x & (SPLIT - 1);
    const int qb    = blockIdx.x >> 2;
    const int d0    = split * DSLICE;
    const int q0    = qb * QPB + wave * TQ;

    // stage proto[:, d0..d0+128) -> LDS, swizzled (f ^ (c&7)) per G4 pattern.
    // global: each 32-lane half reads 512B contiguous (coalesced).
    // LDS write: permutation within each 512B row -> conflict-free.
    const float4* proto4 = (const float4*)proto;
#pragma unroll
    for (int k = 0; k < (CN * F4S) / THREADS; ++k) {   // 8 iters
        int i = tid + k * THREADS;
        int c = i >> 5;
        int f = i & 31;
        plds[c * F4S + (f ^ (c & 7))] = proto4[c * (DN / 4) + (d0 >> 2) + f];
    }
    __syncthreads();

    float acc[TQ];
#pragma unroll
    for (int i = 0; i < TQ; ++i) acc[i] = 0.f;

    const float4* xb = (const float4*)(x + (size_t)q0 * DN + d0);  // wave-uniform
    const float4* pB = plds + lane * F4S;
    const int ls = lane & 7;

#pragma unroll
    for (int f = 0; f < F4S; ++f) {
        float4 p = pB[f ^ ls];              // swizzled ds_read_b128, conflict-free
#pragma unroll
        for (int qi = 0; qi < TQ; ++qi) {
            float4 a = xb[qi * (DN / 4) + f];   // uniform 16B broadcast load
            acc[qi] += fabsf(a.x - p.x) + fabsf(a.y - p.y)
                     + fabsf(a.z - p.z) + fabsf(a.w - p.w);
        }
    }

#pragma unroll
    for (int qi = 0; qi < TQ; ++qi)
        partial[((size_t)split * QN + q0 + qi) * CN + lane] = acc[qi];
}

// --- softmax kernel: wave = one query; sum 4 partials, softmax over lanes ---
__global__ __launch_bounds__(THREADS, 4) void softmax_kernel(
        const float* __restrict__ partial,
        float* __restrict__ out) {
    const int tid  = threadIdx.x;
    const int lane = tid & 63;
    const int wave = tid >> 6;
    const int q    = blockIdx.x * NWAVES + wave;

    float s = 0.f;
#pragma unroll
    for (int sp = 0; sp < SPLIT; ++sp)
        s += partial[((size_t)sp * QN + q) * CN + lane];

    float nd = -s;
    float m = nd;
#pragma unroll
    for (int off = 32; off; off >>= 1)
        m = fmaxf(m, __shfl_xor(m, off, 64));
    float e = __expf(nd - m);
    float t = e;
#pragma unroll
    for (int off = 32; off; off >>= 1)
        t += __shfl_xor(t, off, 64);
    out[(size_t)q * CN + lane] = e / t;
}

extern "C" void kernel_launch(void* const* d_in, const int* in_sizes, int n_in,
                              void* d_out, int out_size, void* d_ws, size_t ws_size,
                              hipStream_t stream) {
    const float* x = (const float*)d_in[0];   // [8192, 512]
    const float* y = (const float*)d_in[1];   // [64, 5, 512]
    float* out     = (float*)d_out;           // [8192, 64]
    float* proto   = (float*)d_ws;                      // 128 KiB
    float* partial = (float*)d_ws + (size_t)CN * DN;    // 4 x 8192 x 64 f32 = 8 MiB

    proto_kernel<<<(CN * DN + 255) / 256, 256, 0, stream>>>(y, proto);
    dist_kernel<<<(QN / QPB) * SPLIT, THREADS, 0, stream>>>(x, proto, partial);
    softmax_kernel<<<QN / NWAVES, THREADS, 0, stream>>>(partial, out);
}